// Round 3
// baseline (41.740 us; speedup 1.0000x reference)
//
#include <hip/hip_runtime.h>
#include <hip/hip_bf16.h>

// y = upsample_nearest_2x2x2(conv1x1(x,W,b)); conv on small grid via bf16 MFMA, replicate 8x.
// x: [2][320][16][32][32] f32, W: [160][320] f32, b: [160] f32 -> out: [2][160][32][64][64] f32
// Grid: 1024 blocks = 256 spatial tiles x 2 batches x 2 output-channel halves.
// Sibling blocks (same tile, different o-half) are 8 apart in blockIdx -> same XCD L2.

#define CI     320
#define CO     160
#define COH    80         // per-block output channels
#define S_IN   16384      // 16*32*32
#define KC     64         // K chunk = 2 MFMA K-steps
#define NT     64         // spatial tile per block
#define NCHUNK (CI / KC)  // 5
#define MT     (COH / 16) // 5 M-tiles per wave

typedef __attribute__((ext_vector_type(8))) short short8;
typedef __attribute__((ext_vector_type(4))) float f32x4;

static __device__ __forceinline__ unsigned short f2bf(float f) {
    __hip_bfloat16 h = __float2bfloat16(f);   // RNE
    unsigned short u;
    __builtin_memcpy(&u, &h, 2);
    return u;
}
static __device__ __forceinline__ unsigned int pack2(float lo, float hi) {
    return (unsigned int)f2bf(lo) | ((unsigned int)f2bf(hi) << 16);
}

__global__ __launch_bounds__(256, 4) void fused_upconv_mfma(
    const float* __restrict__ x,
    const float* __restrict__ Wm,
    const float* __restrict__ bias,
    float* __restrict__ out)
{
    // bf16 tiles as u32 pairs, rows padded 32 -> 36 u32 (144 B: 16B-aligned, banks rotate by 4)
    __shared__ unsigned int XsU[NT][36];    // [s][k/2]   9.0 KB
    __shared__ unsigned int WsU[COH][36];   // [o][k/2]  11.25 KB

    const int t  = threadIdx.x;
    const int bx = blockIdx.x;              // 0..1023
    // decode: groups of 16 consecutive blocks = 8 tile-units x 2 o-halves,
    // pair members (bx, bx+8) share tile-unit and XCD (bx % 8).
    const int g    = bx >> 4;
    const int r    = bx & 15;
    const int oh   = r >> 3;                // o-half 0/1
    const int tu   = g * 8 + (r & 7);       // 0..511 tile-unit
    const int tile = tu & 255;
    const int b    = tu >> 8;

    const int s_base = tile * NT;
    const float* xb  = x + (size_t)b * CI * S_IN;
    const int o_base = oh * COH;

    // ---- staging maps ----
    // X: kp = t>>4 (16 k-quads), s4 = (t&15)*4 : 4 float4 loads (k=4kp..4kp+3, 4 s each)
    const int kp = t >> 4;
    const int s4 = (t & 15) * 4;
    // W: 5 iters, idx = t + it*256 : o = idx>>4, kq = idx&15 : 1 float4 load each
    float4 xr[4];
    float4 wr[5];

    // prefetch chunk 0
    {
        #pragma unroll
        for (int p = 0; p < 4; ++p)
            xr[p] = *(const float4*)&xb[(size_t)(4 * kp + p) * S_IN + s_base + s4];
        #pragma unroll
        for (int it = 0; it < 5; ++it) {
            const int idx = t + it * 256;
            wr[it] = *(const float4*)&Wm[(size_t)(o_base + (idx >> 4)) * CI + (idx & 15) * 4];
        }
    }

    // ---- fragment indices ----
    const int lane = t & 63;
    const int wid  = t >> 6;        // wave id 0..3 -> 16-s subtile
    const int frow = lane & 15;
    const int fk   = lane >> 4;

    f32x4 acc[MT];
    #pragma unroll
    for (int mt = 0; mt < MT; ++mt) acc[mt] = (f32x4){0.f, 0.f, 0.f, 0.f};

    const char* xrow = (const char*)(&XsU[wid * 16 + frow][0]) + fk * 16;

    for (int c = 0; c < NCHUNK; ++c) {
        __syncthreads();   // previous chunk's fragment reads complete

        // regs -> LDS (f32->bf16 convert here)
        {
            #pragma unroll
            for (int j = 0; j < 4; ++j) {
                const float a0 = (&xr[0].x)[j], a1 = (&xr[1].x)[j];
                const float a2 = (&xr[2].x)[j], a3 = (&xr[3].x)[j];
                uint2 p = make_uint2(pack2(a0, a1), pack2(a2, a3));
                *(uint2*)&XsU[s4 + j][2 * kp] = p;
            }
            #pragma unroll
            for (int it = 0; it < 5; ++it) {
                const int idx = t + it * 256;
                uint2 p = make_uint2(pack2(wr[it].x, wr[it].y), pack2(wr[it].z, wr[it].w));
                *(uint2*)&WsU[idx >> 4][2 * (idx & 15)] = p;
            }
        }
        __syncthreads();

        // prefetch next chunk (overlaps MFMA below)
        if (c < NCHUNK - 1) {
            const int kc = (c + 1) * KC;
            #pragma unroll
            for (int p = 0; p < 4; ++p)
                xr[p] = *(const float4*)&xb[(size_t)(kc + 4 * kp + p) * S_IN + s_base + s4];
            #pragma unroll
            for (int it = 0; it < 5; ++it) {
                const int idx = t + it * 256;
                wr[it] = *(const float4*)&Wm[(size_t)(o_base + (idx >> 4)) * CI + kc + (idx & 15) * 4];
            }
        }

        // 2 K-steps x 5 M-tiles
        #pragma unroll
        for (int st = 0; st < 2; ++st) {
            const short8 bfrag = *(const short8*)(xrow + st * 64);
            #pragma unroll
            for (int mt = 0; mt < MT; ++mt) {
                const short8 afrag =
                    *(const short8*)((const char*)(&WsU[mt * 16 + frow][0]) + st * 64 + fk * 16);
                acc[mt] = __builtin_amdgcn_mfma_f32_16x16x32_bf16(afrag, bfrag, acc[mt], 0, 0, 0);
            }
        }
    }

    // ---- epilogue: bias + replicate 8x; shfl-pair -> full float4 nontemporal stores ----
    const int s   = s_base + wid * 16 + frow;   // D col = s
    const int dd  = s >> 10;
    const int hh  = (s >> 5) & 31;
    const int wc  = s & 31;
    const int odd = lane & 1;
    const int wc0 = wc & ~1;

    #pragma unroll
    for (int mt = 0; mt < MT; ++mt) {
        #pragma unroll
        for (int j = 0; j < 4; ++j) {
            const int o = o_base + mt * 16 + fk * 4 + j;  // D row = o (within half)
            float v  = acc[mt][j] + bias[o];
            float vp = __shfl_xor(v, 1);
            float lo = odd ? vp : v;
            float hi = odd ? v : vp;
            f32x4 q = {lo, lo, hi, hi};
            const size_t base = (((size_t)(b * CO + o) * 32) + (size_t)(2 * dd + odd)) * 4096
                              + (size_t)(2 * hh) * 64 + (size_t)(2 * wc0);
            __builtin_nontemporal_store(q, (f32x4*)&out[base]);
            __builtin_nontemporal_store(q, (f32x4*)&out[base + 64]);
        }
    }
}

extern "C" void kernel_launch(void* const* d_in, const int* in_sizes, int n_in,
                              void* d_out, int out_size, void* d_ws, size_t ws_size,
                              hipStream_t stream) {
    const float* x    = (const float*)d_in[0];
    const float* Wm   = (const float*)d_in[1];
    const float* bias = (const float*)d_in[2];
    float* out        = (float*)d_out;

    dim3 grid(1024);
    dim3 block(256);
    fused_upconv_mfma<<<grid, block, 0, stream>>>(x, Wm, bias, out);
}